// Round 1
// baseline (3395.644 us; speedup 1.0000x reference)
//
#include <hip/hip_runtime.h>

#define W_IMG 256
#define H_IMG 256
#define HW_IMG 65536

// Register-blocked direct 3x3 conv (stride 1, pad 1).
// Block: 256 threads covering a 32(w) x 8(h) pixel tile, 64 output channels.
// Thread: 16 out-channels x 4 consecutive pixels -> 64 fp32 accumulators.
// MODE 0: bias+relu, store.  MODE 1: bias only, store.  MODE 2: bias+relu, spatial-sum via atomics (no store).
template <int CIN, int MODE>
__global__ __launch_bounds__(256, 2) void conv3x3_kernel(
    const float* __restrict__ inA, const float* __restrict__ inB,
    const float* __restrict__ wg, const float* __restrict__ bias,
    float* __restrict__ outp, float* __restrict__ red,
    int in_row0, int H_out, int COUT)
{
    const int tid   = threadIdx.x;
    const int pg    = tid & 63;   // pixel group 0..63
    const int ocg_t = tid >> 6;   // 0..3: which 16-channel slice
    const int row_l = pg >> 3;    // 0..7
    const int colg  = pg & 7;     // 0..7 -> cols 4*colg..+3
    const int n_ocg = COUT >> 6;
    const int b     = blockIdx.z / n_ocg;
    const int ocg   = blockIdx.z % n_ocg;
    const int tile_r0 = in_row0 + blockIdx.y * 8; // global input row of tile's first out row
    const int col0  = blockIdx.x * 32;

    __shared__ float xs[16 * 10 * 35];   // [ic][ry 0..9][cx 0..33 (+pad)]
    __shared__ float wsh[16 * 9 * 64];   // [ic][tau][oc]

    float acc[16][4];
#pragma unroll
    for (int o = 0; o < 16; ++o)
#pragma unroll
        for (int k = 0; k < 4; ++k) acc[o][k] = 0.f;

    const int nchunk = CIN >> 4;
    for (int ch = 0; ch < nchunk; ++ch) {
        __syncthreads();
        // ---- stage input tile chunk (16 ch x 10 rows x 34 cols, zero-padded at image border)
        for (int t = tid; t < 16 * 10 * 34; t += 256) {
            int ic  = t / 340;
            int rem = t - ic * 340;
            int ry  = rem / 34;
            int cx  = rem - ry * 34;
            int gr  = tile_r0 + ry - 1;
            int gc  = col0 + cx - 1;
            int cg  = (ch << 4) + ic;
            const float* src = inA;
            int cc = cg;
            if (CIN == 128 && cg >= 64) { src = inB; cc = cg - 64; }
            float v = 0.f;
            if (gr >= 0 && gr < H_IMG && gc >= 0 && gc < W_IMG)
                v = src[((size_t)(b * 64 + cc) * H_IMG + gr) * W_IMG + gc];
            xs[(ic * 10 + ry) * 35 + cx] = v;
        }
        // ---- stage weights chunk: wsh[ic][tau][oc] = wg[oc_g][ch*16+ic][tau]
        for (int t = tid; t < 9216; t += 256) {
            int ic  = t / 576;
            int rem = t - ic * 576;
            int tau = rem >> 6;
            int oc  = rem & 63;
            wsh[t] = wg[((size_t)(ocg * 64 + oc) * CIN + (ch << 4) + ic) * 9 + tau];
        }
        __syncthreads();

        // ---- compute
        for (int ic = 0; ic < 16; ++ic) {
#pragma unroll
            for (int dy = 0; dy < 3; ++dy) {
#pragma unroll
                for (int dx = 0; dx < 3; ++dx) {
                    const float* xp = &xs[(ic * 10 + row_l + dy) * 35 + 4 * colg + dx];
                    float xv0 = xp[0], xv1 = xp[1], xv2 = xp[2], xv3 = xp[3];
                    const float* wp = &wsh[(ic * 9 + dy * 3 + dx) * 64 + ocg_t * 16];
#pragma unroll
                    for (int o = 0; o < 16; ++o) {
                        float wv = wp[o];
                        acc[o][0] = fmaf(wv, xv0, acc[o][0]);
                        acc[o][1] = fmaf(wv, xv1, acc[o][1]);
                        acc[o][2] = fmaf(wv, xv2, acc[o][2]);
                        acc[o][3] = fmaf(wv, xv3, acc[o][3]);
                    }
                }
            }
        }
    }

    if (MODE == 2) {
        // relu then spatial sum (for GAP). Wave == ocg_t slice: 64 lanes cover all 256 tile pixels.
#pragma unroll
        for (int o = 0; o < 16; ++o) {
            float bb = bias[ocg_t * 16 + o];
            float s = fmaxf(acc[o][0] + bb, 0.f) + fmaxf(acc[o][1] + bb, 0.f) +
                      fmaxf(acc[o][2] + bb, 0.f) + fmaxf(acc[o][3] + bb, 0.f);
#pragma unroll
            for (int off = 32; off > 0; off >>= 1) s += __shfl_xor(s, off, 64);
            if (pg == 0) atomicAdd(&red[b * 64 + ocg_t * 16 + o], s);
        }
    } else {
        const int r_out = blockIdx.y * 8 + row_l;
#pragma unroll
        for (int o = 0; o < 16; ++o) {
            const int oc_g = ocg * 64 + ocg_t * 16 + o;
            float bb = bias[oc_g];
            float* op = outp + ((size_t)(b * COUT + oc_g) * H_out + r_out) * W_IMG + col0 + 4 * colg;
#pragma unroll
            for (int k = 0; k < 4; ++k) {
                float v = acc[o][k] + bb;
                if (MODE == 0) v = fmaxf(v, 0.f);
                op[k] = v;
            }
        }
    }
}

// dw[b][n] = sum_k h[b][k]/65536 * w2[n][k] + b2[n];  n in [0,4096)
__global__ void dw_gemm_kernel(const float* __restrict__ hsum, const float* __restrict__ w2,
                               const float* __restrict__ b2, float* __restrict__ dwout)
{
    __shared__ float h[64];
    int idx = blockIdx.x * 256 + threadIdx.x;
    int b = idx >> 12;
    int n = idx & 4095;
    if (threadIdx.x < 64) h[threadIdx.x] = hsum[b * 64 + threadIdx.x] * (1.f / 65536.f);
    __syncthreads();
    float a = 0.f;
#pragma unroll
    for (int k = 0; k < 64; ++k) a = fmaf(h[k], w2[(size_t)n * 64 + k], a);
    dwout[idx] = a + b2[n];
}

// One block per (row-in-slab, batch); thread = column.
// y[c] = sum_j cw[c*9+j] * patch(c,j); z[o] = sum_c dw[b][o*64+c] * y[c]; + BN stats atomics.
__global__ __launch_bounds__(256, 2) void yz_kernel(
    const float* __restrict__ input, const float* __restrict__ cw_slab,
    const float* __restrict__ dwv, float* __restrict__ z,
    float* __restrict__ s1, float* __restrict__ s2, int slab0, int SLAB)
{
    const int col = threadIdx.x;
    const int r_l = blockIdx.x;
    const int b   = blockIdx.y;
    const int R   = slab0 + r_l;

    __shared__ float dws[4096];
    for (int t = threadIdx.x; t < 4096; t += 256) dws[t] = dwv[b * 4096 + t];
    __syncthreads();

    float y[64];
#pragma unroll
    for (int c = 0; c < 64; ++c) {
        float a = 0.f;
#pragma unroll
        for (int j = 0; j < 9; ++j) {
            const int dy = j / 3 - 1, dx = j % 3 - 1;
            float cwv = cw_slab[((size_t)(b * 576 + c * 9 + j) * SLAB + r_l) * W_IMG + col];
            const int rr = R + dy, cc = col + dx;
            float ev = 0.f;
            if (rr >= 0 && rr < H_IMG && cc >= 0 && cc < W_IMG)
                ev = input[((size_t)(b * 64 + c) * H_IMG + rr) * W_IMG + cc];
            a = fmaf(cwv, ev, a);
        }
        y[c] = a;
    }

    float* zp = z + (size_t)b * 64 * HW_IMG + (size_t)R * W_IMG + col;
    for (int o = 0; o < 64; ++o) {
        float zv = 0.f;
#pragma unroll
        for (int c = 0; c < 64; ++c) zv = fmaf(dws[o * 64 + c], y[c], zv);
        zp[(size_t)o * HW_IMG] = zv;
        float a1 = zv, a2 = zv * zv;
#pragma unroll
        for (int off = 32; off > 0; off >>= 1) {
            a1 += __shfl_xor(a1, off, 64);
            a2 += __shfl_xor(a2, off, 64);
        }
        if ((threadIdx.x & 63) == 0) { atomicAdd(&s1[o], a1); atomicAdd(&s2[o], a2); }
    }
}

// BN (training-mode batch stats) + ReLU, in-place over z (= d_out). 4 elems/thread.
__global__ void bn_kernel(const float* __restrict__ z, const float* __restrict__ s1,
                          const float* __restrict__ s2, const float* __restrict__ gamma,
                          const float* __restrict__ beta, float* __restrict__ outp)
{
    size_t idx = ((size_t)blockIdx.x * 256 + threadIdx.x) * 4;
    int o = (int)((idx >> 16) & 63);
    float mu  = s1[o] * (1.f / 131072.f);
    float var = s2[o] * (1.f / 131072.f) - mu * mu;
    float rs  = rsqrtf(var + 1e-5f);
    float scale = gamma[o] * rs;
    float shift = beta[o] - mu * scale;
    float4 v = *(const float4*)(z + idx);
    v.x = fmaxf(v.x * scale + shift, 0.f);
    v.y = fmaxf(v.y * scale + shift, 0.f);
    v.z = fmaxf(v.z * scale + shift, 0.f);
    v.w = fmaxf(v.w * scale + shift, 0.f);
    *(float4*)(outp + idx) = v;
}

extern "C" void kernel_launch(void* const* d_in, const int* in_sizes, int n_in,
                              void* d_out, int out_size, void* d_ws, size_t ws_size,
                              hipStream_t stream)
{
    const float* input    = (const float*)d_in[0];
    const float* guidance = (const float*)d_in[1];
    const float* cw_w1    = (const float*)d_in[2];
    const float* cw_b1    = (const float*)d_in[3];
    const float* cw_w2    = (const float*)d_in[4];
    const float* cw_b2    = (const float*)d_in[5];
    const float* dw_w1    = (const float*)d_in[6];
    const float* dw_b1    = (const float*)d_in[7];
    const float* dw_w2    = (const float*)d_in[8];
    const float* dw_b2    = (const float*)d_in[9];
    const float* gamma    = (const float*)d_in[10];
    const float* beta     = (const float*)d_in[11];
    float* outp = (float*)d_out;  // doubles as the z buffer

    char* ws = (char*)d_ws;
    float* t1    = (float*)ws;                    // relu(conv1_cw): 33,554,432 B
    float* hsum  = (float*)(ws + 33554432);       // [2][64] atomics (zeroed)
    float* s1    = (float*)(ws + 33555456);       // [64] BN sum (zeroed, with s2)
    float* s2    = (float*)(ws + 33555712);       // [64] BN sumsq
    float* dwbuf = (float*)(ws + 33556480);       // [2][4096]
    float* cwsl  = (float*)(ws + 33589248);       // cw slab: 2*576*SLAB*256*4 B

    const size_t fixed = 33589248;
    int SLAB = 64;                                // rows per cw slab (must be multiple of 8)
    while (SLAB > 8 && fixed + (size_t)SLAB * 1179648 > ws_size) SLAB >>= 1;

    hipMemsetAsync(hsum, 0, 512, stream);  // h_sum
    hipMemsetAsync(s1, 0, 512, stream);    // s1 + s2

    dim3 blk(256, 1, 1);
    // conv1 (cw path): concat(input,guidance) -> relu -> t1
    conv3x3_kernel<128, 0><<<dim3(8, 32, 2), blk, 0, stream>>>(
        input, guidance, cw_w1, cw_b1, t1, nullptr, 0, 256, 64);
    // conv1 (dw path): concat -> relu -> spatial sum (GAP numerator)
    conv3x3_kernel<128, 2><<<dim3(8, 32, 2), blk, 0, stream>>>(
        input, guidance, dw_w1, dw_b1, nullptr, hsum, 0, 256, 64);
    // dw 1x1 conv on pooled vector
    dw_gemm_kernel<<<dim3(32), blk, 0, stream>>>(hsum, dw_w2, dw_b2, dwbuf);

    // conv2 (576-ch) computed per row-slab, immediately consumed by yz
    for (int s = 0; s < 256 / SLAB; ++s) {
        int slab0 = s * SLAB;
        conv3x3_kernel<64, 1><<<dim3(8, SLAB / 8, 18), blk, 0, stream>>>(
            t1, nullptr, cw_w2, cw_b2, cwsl, nullptr, slab0, SLAB, 576);
        yz_kernel<<<dim3(SLAB, 2), blk, 0, stream>>>(
            input, cwsl, dwbuf, outp, s1, s2, slab0, SLAB);
    }

    // BN + ReLU in-place on d_out
    bn_kernel<<<dim3(8192), blk, 0, stream>>>(outp, s1, s2, gamma, beta, outp);
}

// Round 3
// 548.073 us; speedup vs baseline: 6.1956x; 6.1956x over previous
//
#include <hip/hip_runtime.h>

typedef short v8s __attribute__((ext_vector_type(8)));
typedef float v4f __attribute__((ext_vector_type(4)));

__device__ inline unsigned short f2bf(float f) {
    unsigned u = __float_as_uint(f);
    u += 0x7fff + ((u >> 16) & 1);
    return (unsigned short)(u >> 16);
}

// async global->LDS, 16B per lane. LDS dest is wave-uniform base; HW adds lane*16.
__device__ inline void gload_lds16(const void* g, void* l) {
    __builtin_amdgcn_global_load_lds(
        (const __attribute__((address_space(1))) unsigned*)(unsigned long long)(uintptr_t)g,
        (__attribute__((address_space(3))) unsigned*)(unsigned)(uintptr_t)l, 16, 0, 0);
}

// ---------------------------------------------------------------------------
// transpose: NCHW fp32 input+guidance -> X0 [b][r][px][128c] swizzled bf16 (256B/px,
// rotation 16*(px&7)) and inN [b][r][px][64c] bf16 unswizzled (for yz patches).
__global__ void transpose_kernel(const float* __restrict__ input, const float* __restrict__ guidance,
                                 char* __restrict__ X0, char* __restrict__ inN)
{
    const int r = blockIdx.x, b = blockIdx.y, px = threadIdx.x;
    const size_t hw = (size_t)r * 256 + px;
    char* xrow = X0 + (((size_t)b * 65536 + hw) << 8);
    char* irow = inN + (((size_t)b * 65536 + hw) << 7);
    const int rot = (px & 7) << 4;
    for (int c8 = 0; c8 < 16; ++c8) {
        unsigned sh[4];
#pragma unroll
        for (int e = 0; e < 8; e += 2) {
            int c0 = c8 * 8 + e;
            float f0 = (c0 < 64) ? input[(((size_t)(b * 64 + c0)) << 16) + hw]
                                 : guidance[(((size_t)(b * 64 + c0 - 64)) << 16) + hw];
            float f1 = (c0 + 1 < 64) ? input[(((size_t)(b * 64 + c0 + 1)) << 16) + hw]
                                     : guidance[(((size_t)(b * 64 + c0 - 63)) << 16) + hw];
            sh[e >> 1] = (unsigned)f2bf(f0) | ((unsigned)f2bf(f1) << 16);
        }
        uint4 pk = make_uint4(sh[0], sh[1], sh[2], sh[3]);
        *(uint4*)(xrow + ((c8 * 16 + rot) & 255)) = pk;
        if (c8 < 8) *(uint4*)(irow + c8 * 16) = pk;
    }
}

// ---------------------------------------------------------------------------
// prepack weights [COUT][CIN][3][3] fp32 -> bf16 B-fragments
// layout [tau][ick][ng][lane][8j]: B[k][n], n=ng*16+(lane&15), k=ick*32+(lane>>4)*8+j
// PERM (conv2): our N-index n -> real oc = (n%64)*9 + n/64  (j-major cw layout)
template <int CIN, int COUT, bool PERM>
__global__ void prepack_kernel(const float* __restrict__ src, char* __restrict__ dst)
{
    constexpr int ICK = CIN / 32, NGT = COUT / 16;
    int t = blockIdx.x * 256 + threadIdx.x;
    int jj = t & 7, lane = (t >> 3) & 63;
    int r2 = t >> 9;
    int ng = r2 % NGT, r3 = r2 / NGT;
    int ick = r3 % ICK, tau = r3 / ICK;
    if (tau >= 9) return;
    int n  = ng * 16 + (lane & 15);
    int ic = ick * 32 + (lane >> 4) * 8 + jj;
    int oc = PERM ? ((n & 63) * 9 + (n >> 6)) : n;
    float v = src[(((size_t)oc * CIN + ic) * 3 + tau / 3) * 3 + tau % 3];
    *(unsigned short*)(dst + (size_t)t * 2) = f2bf(v);
}

__global__ void biasperm_kernel(const float* __restrict__ src, float* __restrict__ dst) {
    int t = blockIdx.x * 192 + threadIdx.x;
    if (t < 576) dst[t] = src[(t & 63) * 9 + (t >> 6)];
}

// ---------------------------------------------------------------------------
// MFMA 3x3 conv, stride 1 pad 1. Block = 256 thr (4 waves), 64-px tile (quarter row),
// all COUT at once; wave w covers n' groups [w*NGW, (w+1)*NGW). K = 9 taus x (CIN/32).
// BST ksteps of B staged per barrier pair (16 MFMAs/barrier for conv1, 36 for conv2).
// MODE 0: relu, store swizzled NHWC bf16 (t1). MODE 1: +bias, store [b][rloc][px][oc'] bf16.
// MODE 2: relu + spatial sum -> atomics (GAP).
template <int CIN, int COUT, int MODE>
__global__ __launch_bounds__(256, 2) void conv_mfma(
    const char* __restrict__ Asrc, const char* __restrict__ Bp,
    const float* __restrict__ bias, char* __restrict__ outp,
    float* __restrict__ red, int slab0, int SLAB)
{
    constexpr int CINB = CIN * 2;
    constexpr int ICK  = CIN / 32;
    constexpr int NGW  = COUT / 64;      // 16-col groups per wave
    constexpr int PP   = 66 * CINB;      // plane bytes
    constexpr int BSZ  = COUT * 64;      // bytes of one B k-step
    constexpr int BST  = (CIN == 128) ? ICK : 1;   // ksteps staged per barrier pair

    __shared__ __align__(16) char As[3 * PP];
    __shared__ __align__(16) char Bs[BST * BSZ];
    __shared__ float biasS[(MODE == 1) ? COUT : 16];

    const int tid  = threadIdx.x;
    const int lane = tid & 63;
    const int w    = tid >> 6;
    const int m16  = lane & 15, q = lane >> 4;
    const int col0 = blockIdx.x * 64;
    const int row  = slab0 + blockIdx.y;
    const int b    = blockIdx.z;

    if (MODE == 1) for (int t = tid; t < COUT; t += 256) biasS[t] = bias[t];

    // stage 3 input planes (rows row-1..row+1), cols col0-1..col0+64, edge-clamped
    const char* rowbase = Asrc + ((size_t)b * 65536) * CINB;
    constexpr int PP16 = PP / 16;
    for (int idx = tid; idx < 3 * PP16; idx += 256) {
        int plane = idx / PP16;
        int gr = row + plane - 1;
        if ((unsigned)gr < 256u) {
            int wb  = (idx - plane * PP16) * 16;
            int pxo = wb / CINB;
            int gpx = min(max(col0 - 1 + pxo, 0), 255);
            const char* src = rowbase + ((size_t)gr * 256 + gpx) * CINB + (wb & (CINB - 1));
            gload_lds16(src, As + (idx & ~63) * 16);
        }
    }
    __syncthreads();
    // zero halo columns at image borders (overwrites clamped garbage)
    constexpr int NZ = CINB / 16;
    if (col0 == 0 && tid < 3 * NZ)
        *(uint4*)(As + (tid / NZ) * PP + (tid % NZ) * 16) = make_uint4(0, 0, 0, 0);
    if (col0 + 64 == 256 && tid < 3 * NZ)
        *(uint4*)(As + (tid / NZ) * PP + 65 * CINB + (tid % NZ) * 16) = make_uint4(0, 0, 0, 0);

    v4f acc[4][NGW];
#pragma unroll
    for (int mg = 0; mg < 4; ++mg)
#pragma unroll
        for (int ng = 0; ng < NGW; ++ng) acc[mg][ng] = (v4f)(0.f);

    for (int ty = 0; ty < 3; ++ty) {
        int gr = row + ty - 1;
        if ((unsigned)gr >= 256u) continue;          // uniform per block
        const char* plane = As + ty * PP;
        for (int tx = 0; tx < 3; ++tx) {
            for (int ick0 = 0; ick0 < ICK; ick0 += BST) {
                __syncthreads();
                {
                    const char* bsrc = Bp + (size_t)((ty * 3 + tx) * ICK + ick0) * BSZ;
                    for (int idx = tid; idx < BST * BSZ / 16; idx += 256)
                        gload_lds16(bsrc + idx * 16, Bs + (idx & ~63) * 16);
                }
                __syncthreads();
#pragma unroll
                for (int ii = 0; ii < BST; ++ii) {
                    const int ick = ick0 + ii;
                    v8s af[4];
#pragma unroll
                    for (int mg = 0; mg < 4; ++mg) {
                        int px  = col0 + mg * 16 + m16 + tx - 1;       // global pixel read
                        int tpx = mg * 16 + m16 + tx;                  // tile slot
                        int off = (ick * 64 + q * 16 + ((px & 7) << 4)) & (CINB - 1);
                        af[mg] = *(const v8s*)(plane + tpx * CINB + off);
                    }
#pragma unroll
                    for (int ng = 0; ng < NGW; ++ng) {
                        v8s bf = *(const v8s*)(Bs + ii * BSZ + ((w * NGW + ng) << 10) + (lane << 4));
#pragma unroll
                        for (int mg = 0; mg < 4; ++mg)
                            acc[mg][ng] = __builtin_amdgcn_mfma_f32_16x16x32_bf16(af[mg], bf, acc[mg][ng], 0, 0, 0);
                    }
                }
            }
        }
    }

    if (MODE == 2) {
        float bb = bias[w * 16 + m16];
        float s = 0.f;
#pragma unroll
        for (int mg = 0; mg < 4; ++mg)
#pragma unroll
            for (int r = 0; r < 4; ++r) s += fmaxf(acc[mg][0][r] + bb, 0.f);
        s += __shfl_xor(s, 16, 64);
        s += __shfl_xor(s, 32, 64);
        if (lane < 16) atomicAdd(&red[b * 64 + w * 16 + m16], s);
    } else if (MODE == 0) {
        int oc = w * 16 + m16;
        float bb = bias[oc];
        char* dst = outp + ((size_t)(b * 256 + row) * 256) * 128;
#pragma unroll
        for (int mg = 0; mg < 4; ++mg)
#pragma unroll
            for (int r = 0; r < 4; ++r) {
                int px = col0 + mg * 16 + (q << 2) + r;
                float v = fmaxf(acc[mg][0][r] + bb, 0.f);
                *(unsigned short*)(dst + (size_t)px * 128 + ((oc * 2 + ((px & 7) << 4)) & 127)) = f2bf(v);
            }
    } else {
        int rloc = row - slab0;
#pragma unroll
        for (int ng = 0; ng < NGW; ++ng) {
            int ocp = (w * NGW + ng) * 16 + m16;
            float bb = biasS[ocp];
#pragma unroll
            for (int mg = 0; mg < 4; ++mg)
#pragma unroll
                for (int r = 0; r < 4; ++r) {
                    int px = col0 + mg * 16 + (q << 2) + r;
                    size_t e = ((size_t)(b * SLAB + rloc) * 256 + px) * 576 + ocp;
                    *(unsigned short*)(outp + e * 2) = f2bf(acc[mg][ng][r] + bb);
                }
        }
    }
}

// ---------------------------------------------------------------------------
// dw[b][n] = sum_k h[b][k]/65536 * w2[n][k] + b2[n]
__global__ void dw_gemm_kernel(const float* __restrict__ hsum, const float* __restrict__ w2,
                               const float* __restrict__ b2, float* __restrict__ dwout)
{
    __shared__ float h[64];
    int idx = blockIdx.x * 256 + threadIdx.x;
    int b = idx >> 12, n = idx & 4095;
    if (threadIdx.x < 64) h[threadIdx.x] = hsum[b * 64 + threadIdx.x] * (1.f / 65536.f);
    __syncthreads();
    float a = 0.f;
#pragma unroll
    for (int k = 0; k < 64; ++k) a = fmaf(h[k], w2[(size_t)n * 64 + k], a);
    dwout[idx] = a + b2[n];
}

// ---------------------------------------------------------------------------
// yz: y[c] = sum_j cw[px][j*64+c]*inN[px+off(j)][c]; z[o] = sum_c dw[o][c]*y[c]
__global__ __launch_bounds__(256) void yz_kernel(
    const char* __restrict__ inN, const char* __restrict__ cw,
    const float* __restrict__ dwv, float* __restrict__ z, int slab0, int SLAB)
{
    const int px = threadIdx.x;
    const int rloc = blockIdx.x, b = blockIdx.y;
    const int row = slab0 + rloc;

    __shared__ float dws[4096];
    for (int t = px; t < 4096; t += 256) dws[t] = dwv[b * 4096 + t];

    float y[64];
#pragma unroll
    for (int c = 0; c < 64; ++c) y[c] = 0.f;

    const char* cwp = cw + (((size_t)(b * SLAB + rloc) * 256 + px) * 576) * 2;
#pragma unroll
    for (int j = 0; j < 9; ++j) {
        int rr = row + j / 3 - 1, cc = px + j % 3 - 1;
        if ((unsigned)rr >= 256u || (unsigned)cc >= 256u) continue;
        const char* ip = inN + (((size_t)(b * 256 + rr) * 256 + cc) << 7);
        const char* cp = cwp + j * 128;
#pragma unroll
        for (int i = 0; i < 8; ++i) {
            uint4 xv = *(const uint4*)(ip + i * 16);
            uint4 wv = *(const uint4*)(cp + i * 16);
            const unsigned* xu = &xv.x;
            const unsigned* wu = &wv.x;
#pragma unroll
            for (int d = 0; d < 4; ++d) {
                float x0 = __uint_as_float(xu[d] << 16);
                float x1 = __uint_as_float(xu[d] & 0xffff0000u);
                float w0 = __uint_as_float(wu[d] << 16);
                float w1 = __uint_as_float(wu[d] & 0xffff0000u);
                y[i * 8 + d * 2]     = fmaf(x0, w0, y[i * 8 + d * 2]);
                y[i * 8 + d * 2 + 1] = fmaf(x1, w1, y[i * 8 + d * 2 + 1]);
            }
        }
    }
    __syncthreads();
    float* zp = z + ((size_t)b << 22) + ((size_t)row << 8) + px;
#pragma unroll 4
    for (int o = 0; o < 64; ++o) {
        float zv = 0.f;
#pragma unroll
        for (int c = 0; c < 64; ++c) zv = fmaf(dws[o * 64 + c], y[c], zv);
        zp[(size_t)o << 16] = zv;
    }
}

// ---------------------------------------------------------------------------
// BN stats over z[b][o][hw]: grid (64 o, 8 chunks of 8192). Exact-fit indexing.
__global__ void stats_kernel(const float* __restrict__ z, float* __restrict__ s1, float* __restrict__ s2)
{
    int o = blockIdx.x, ch = blockIdx.y;
    float a1 = 0.f, a2 = 0.f;
    for (int t = threadIdx.x; t < 8192; t += 256) {
        float v0 = z[((size_t)o << 16) + (ch << 13) + t];
        float v1 = z[((size_t)(64 + o) << 16) + (ch << 13) + t];
        a1 += v0 + v1;
        a2 += v0 * v0 + v1 * v1;
    }
#pragma unroll
    for (int d = 32; d > 0; d >>= 1) { a1 += __shfl_xor(a1, d, 64); a2 += __shfl_xor(a2, d, 64); }
    __shared__ float r1[4], r2[4];
    int w = threadIdx.x >> 6;
    if ((threadIdx.x & 63) == 0) { r1[w] = a1; r2[w] = a2; }
    __syncthreads();
    if (threadIdx.x == 0) {
        atomicAdd(&s1[o], r1[0] + r1[1] + r1[2] + r1[3]);
        atomicAdd(&s2[o], r2[0] + r2[1] + r2[2] + r2[3]);
    }
}

__global__ void bn_kernel(const float* __restrict__ z, const float* __restrict__ s1,
                          const float* __restrict__ s2, const float* __restrict__ gamma,
                          const float* __restrict__ beta, float* __restrict__ outp)
{
    size_t idx = ((size_t)blockIdx.x * 256 + threadIdx.x) * 4;
    int o = (int)((idx >> 16) & 63);
    float mu  = s1[o] * (1.f / 131072.f);
    float var = s2[o] * (1.f / 131072.f) - mu * mu;
    float rs  = rsqrtf(var + 1e-5f);
    float scale = gamma[o] * rs;
    float shift = beta[o] - mu * scale;
    float4 v = *(const float4*)(z + idx);
    v.x = fmaxf(v.x * scale + shift, 0.f);
    v.y = fmaxf(v.y * scale + shift, 0.f);
    v.z = fmaxf(v.z * scale + shift, 0.f);
    v.w = fmaxf(v.w * scale + shift, 0.f);
    *(float4*)(outp + idx) = v;
}

// ---------------------------------------------------------------------------
extern "C" void kernel_launch(void* const* d_in, const int* in_sizes, int n_in,
                              void* d_out, int out_size, void* d_ws, size_t ws_size,
                              hipStream_t stream)
{
    const float* input    = (const float*)d_in[0];
    const float* guidance = (const float*)d_in[1];
    const float* cw_w1    = (const float*)d_in[2];
    const float* cw_b1    = (const float*)d_in[3];
    const float* cw_w2    = (const float*)d_in[4];
    const float* cw_b2    = (const float*)d_in[5];
    const float* dw_w1    = (const float*)d_in[6];
    const float* dw_b1    = (const float*)d_in[7];
    const float* dw_w2    = (const float*)d_in[8];
    const float* dw_b2    = (const float*)d_in[9];
    const float* gamma    = (const float*)d_in[10];
    const float* beta     = (const float*)d_in[11];

    char* ws = (char*)d_ws;
    char*  inN   = ws;                            // 16,777,216
    char*  t1    = ws + 16777216;                 // 16,777,216
    char*  Bp1   = ws + 33554432;                 // 147,456
    char*  Bpdw  = ws + 33701888;                 // 147,456
    char*  Bp2   = ws + 33849344;                 // 663,552
    float* biasp = (float*)(ws + 34512896);       // 2,304
    float* hsum  = (float*)(ws + 34515200);       // 512
    float* s1    = (float*)(ws + 34515712);       // 256
    float* s2    = (float*)(ws + 34515968);       // 256
    float* dwbuf = (float*)(ws + 34516224);       // 32,768
    char*  cwsl  = ws + 34549248;                 // SLAB*589,824

    int SLAB = 128;
    while (SLAB > 8 && 34549248 + (size_t)SLAB * 589824 > ws_size) SLAB >>= 1;

    char* X0 = (char*)d_out;   // concat bf16 lives in d_out until conv1 done

    hipMemsetAsync(hsum, 0, 1024, stream);   // hsum + s1 + s2

    transpose_kernel<<<dim3(256, 2), 256, 0, stream>>>(input, guidance, X0, inN);
    prepack_kernel<128, 64, false><<<288, 256, 0, stream>>>(cw_w1, Bp1);
    prepack_kernel<128, 64, false><<<288, 256, 0, stream>>>(dw_w1, Bpdw);
    prepack_kernel<64, 576, true><<<1296, 256, 0, stream>>>(cw_w2, Bp2);
    biasperm_kernel<<<3, 192, 0, stream>>>(cw_b2, biasp);

    conv_mfma<128, 64, 0><<<dim3(4, 256, 2), 256, 0, stream>>>(X0, Bp1, cw_b1, t1, nullptr, 0, 1);
    conv_mfma<128, 64, 2><<<dim3(4, 256, 2), 256, 0, stream>>>(X0, Bpdw, dw_b1, nullptr, hsum, 0, 1);
    dw_gemm_kernel<<<32, 256, 0, stream>>>(hsum, dw_w2, dw_b2, dwbuf);

    for (int s0 = 0; s0 < 256; s0 += SLAB) {
        conv_mfma<64, 576, 1><<<dim3(4, SLAB, 2), 256, 0, stream>>>(t1, Bp2, biasp, cwsl, nullptr, s0, SLAB);
        yz_kernel<<<dim3(SLAB, 2), 256, 0, stream>>>(inN, cwsl, dwbuf, (float*)d_out, s0, SLAB);
    }
    stats_kernel<<<dim3(64, 8), 256, 0, stream>>>((const float*)d_out, s1, s2);
    bn_kernel<<<8192, 256, 0, stream>>>((const float*)d_out, s1, s2, gamma, beta, (float*)d_out);
}

// Round 4
// 395.881 us; speedup vs baseline: 8.5774x; 1.3844x over previous
//
#include <hip/hip_runtime.h>

typedef short v8s __attribute__((ext_vector_type(8)));
typedef float v4f __attribute__((ext_vector_type(4)));

__device__ inline unsigned short f2bf(float f) {
    unsigned u = __float_as_uint(f);
    u += 0x7fff + ((u >> 16) & 1);
    return (unsigned short)(u >> 16);
}
__device__ inline float bf2f(unsigned short h) {
    return __uint_as_float(((unsigned)h) << 16);
}

// async global->LDS, 16B per lane. LDS dest is wave-uniform base; HW adds lane*16.
__device__ inline void gload_lds16(const void* g, void* l) {
    __builtin_amdgcn_global_load_lds(
        (const __attribute__((address_space(1))) unsigned*)(unsigned long long)(uintptr_t)g,
        (__attribute__((address_space(3))) unsigned*)(unsigned)(uintptr_t)l, 16, 0, 0);
}

// ---------------------------------------------------------------------------
// transpose: NCHW fp32 input+guidance -> X0 [b][hw][128c] swizzled bf16 (256B/px,
// rot 16*(px&7)) and inN [b][hw][64c] bf16 ALSO rotated (rot&127) for patch reads.
__global__ void transpose_kernel(const float* __restrict__ input, const float* __restrict__ guidance,
                                 char* __restrict__ X0, char* __restrict__ inN)
{
    const int r = blockIdx.x, b = blockIdx.y, px = threadIdx.x;
    const size_t hw = (size_t)r * 256 + px;
    char* xrow = X0 + (((size_t)b * 65536 + hw) << 8);
    char* irow = inN + (((size_t)b * 65536 + hw) << 7);
    const int rot = (px & 7) << 4;
    for (int c8 = 0; c8 < 16; ++c8) {
        unsigned sh[4];
#pragma unroll
        for (int e = 0; e < 8; e += 2) {
            int c0 = c8 * 8 + e;
            float f0 = (c0 < 64) ? input[(((size_t)(b * 64 + c0)) << 16) + hw]
                                 : guidance[(((size_t)(b * 64 + c0 - 64)) << 16) + hw];
            float f1 = (c0 + 1 < 64) ? input[(((size_t)(b * 64 + c0 + 1)) << 16) + hw]
                                     : guidance[(((size_t)(b * 64 + c0 - 63)) << 16) + hw];
            sh[e >> 1] = (unsigned)f2bf(f0) | ((unsigned)f2bf(f1) << 16);
        }
        uint4 pk = make_uint4(sh[0], sh[1], sh[2], sh[3]);
        *(uint4*)(xrow + ((c8 * 16 + rot) & 255)) = pk;
        if (c8 < 8) *(uint4*)(irow + ((c8 * 16 + rot) & 127)) = pk;
    }
}

// ---------------------------------------------------------------------------
// conv1 weight prepack (both sets): [64][128][3][3] fp32 -> bf16 B-fragments
// [tau][ick(4)][ng(4)][lane][8j]: B[k][n], n=ng*16+(lane&15), k=ick*32+(lane>>4)*8+j
__global__ void prepack1_kernel(const float* __restrict__ w1, const float* __restrict__ w2,
                                char* __restrict__ d1, char* __restrict__ d2)
{
    const float* src = blockIdx.y ? w2 : w1;
    char* dst = blockIdx.y ? d2 : d1;
    int t = blockIdx.x * 256 + threadIdx.x;
    int jj = t & 7, lane = (t >> 3) & 63;
    int r2 = t >> 9;
    int ng = r2 & 3, r3 = r2 >> 2;
    int ick = r3 & 3, tau = r3 >> 2;
    if (tau >= 9) return;
    int n  = ng * 16 + (lane & 15);
    int ic = ick * 32 + (lane >> 4) * 8 + jj;
    float v = src[(((size_t)n * 128 + ic) * 3 + tau / 3) * 3 + tau % 3];
    *(unsigned short*)(dst + (size_t)t * 2) = f2bf(v);
}

// conv2 weight prepack: [576][64][3][3] fp32 -> [tau][ick(2)][ng(36)][lane][8j]
// PERM: our N-index n -> real oc = (n%64)*9 + n/64  (so lane gets fixed c, ng = j)
__global__ void prepack2_kernel(const float* __restrict__ src, char* __restrict__ dst)
{
    int t = blockIdx.x * 256 + threadIdx.x;
    int jj = t & 7, lane = (t >> 3) & 63;
    int r2 = t >> 9;
    int ng = r2 % 36, r3 = r2 / 36;
    int ick = r3 & 1, tau = r3 >> 1;
    if (tau >= 9) return;
    int n  = ng * 16 + (lane & 15);
    int ic = ick * 32 + (lane >> 4) * 8 + jj;
    int oc = (n & 63) * 9 + (n >> 6);
    float v = src[(((size_t)oc * 64 + ic) * 3 + tau / 3) * 3 + tau % 3];
    *(unsigned short*)(dst + (size_t)t * 2) = f2bf(v);
}

// ---------------------------------------------------------------------------
// conv1 fused (cw + dw paths share A): CIN=128, two 64-out B sets.
// Block: 64-px tile, 4 waves; wave w = oc group w*16..+16 for BOTH sets.
__global__ __launch_bounds__(256, 2) void conv1_mfma(
    const char* __restrict__ X0, const char* __restrict__ Bp1, const char* __restrict__ Bp2,
    const float* __restrict__ b1, const float* __restrict__ b2,
    char* __restrict__ t1, float* __restrict__ hsum)
{
    constexpr int PP = 66 * 256;          // plane bytes
    __shared__ __align__(16) char As[3 * PP];      // 50688
    __shared__ __align__(16) char Bs[4 * 4096];    // [ii(2)][set(2)][4096]

    const int tid = threadIdx.x, lane = tid & 63, w = tid >> 6;
    const int m16 = lane & 15, q = lane >> 4;
    const int col0 = blockIdx.x * 64;
    const int row  = blockIdx.y;
    const int b    = blockIdx.z;

    const char* rowbase = X0 + ((size_t)b * 65536) * 256;
    for (int idx = tid; idx < 3 * 1056; idx += 256) {
        int plane = idx / 1056;
        int gr = row + plane - 1;
        if ((unsigned)gr < 256u) {
            int wb  = (idx - plane * 1056) * 16;
            int pxo = wb >> 8;
            int gpx = min(max(col0 - 1 + pxo, 0), 255);
            gload_lds16(rowbase + (((size_t)gr * 256 + gpx) << 8) + (wb & 255),
                        As + (idx & ~63) * 16);
        }
    }
    __syncthreads();
    if (col0 == 0 && tid < 48)
        *(uint4*)(As + (tid / 16) * PP + (tid & 15) * 16) = make_uint4(0, 0, 0, 0);
    if (col0 == 192 && tid < 48)
        *(uint4*)(As + (tid / 16) * PP + 65 * 256 + (tid & 15) * 16) = make_uint4(0, 0, 0, 0);

    v4f acc[4][2];
#pragma unroll
    for (int mg = 0; mg < 4; ++mg) { acc[mg][0] = (v4f)(0.f); acc[mg][1] = (v4f)(0.f); }

    for (int ty = 0; ty < 3; ++ty) {
        int gr = row + ty - 1;
        if ((unsigned)gr >= 256u) continue;
        const char* plane = As + ty * PP;
        for (int tx = 0; tx < 3; ++tx) {
            for (int ick0 = 0; ick0 < 4; ick0 += 2) {
                const int kstep = (ty * 3 + tx) * 4 + ick0;
                __syncthreads();
                for (int idx = tid; idx < 1024; idx += 256) {
                    int ii = idx >> 9, set = (idx >> 8) & 1, off16 = idx & 255;
                    const char* src = (set ? Bp2 : Bp1) + (size_t)(kstep + ii) * 4096 + off16 * 16;
                    gload_lds16(src, Bs + (idx & ~63) * 16);
                }
                __syncthreads();
#pragma unroll
                for (int ii = 0; ii < 2; ++ii) {
                    const int ick = ick0 + ii;
                    v8s af[4];
#pragma unroll
                    for (int mg = 0; mg < 4; ++mg) {
                        int px  = col0 + mg * 16 + m16 + tx - 1;
                        int tpx = mg * 16 + m16 + tx;
                        int off = (ick * 64 + q * 16 + ((px & 7) << 4)) & 255;
                        af[mg] = *(const v8s*)(plane + tpx * 256 + off);
                    }
#pragma unroll
                    for (int set = 0; set < 2; ++set) {
                        v8s bf = *(const v8s*)(Bs + ((ii * 2 + set) << 12) + (w << 10) + (lane << 4));
#pragma unroll
                        for (int mg = 0; mg < 4; ++mg)
                            acc[mg][set] = __builtin_amdgcn_mfma_f32_16x16x32_bf16(af[mg], bf, acc[mg][set], 0, 0, 0);
                    }
                }
            }
        }
    }

    const int oc = w * 16 + m16;
    // set 0 -> t1 (relu, rotated NHWC bf16)
    {
        float bb = b1[oc];
        char* dst = t1 + (((size_t)(b * 256 + row)) << 8) * 128;
#pragma unroll
        for (int mg = 0; mg < 4; ++mg)
#pragma unroll
            for (int r = 0; r < 4; ++r) {
                int px = col0 + mg * 16 + (q << 2) + r;
                float v = fmaxf(acc[mg][0][r] + bb, 0.f);
                *(unsigned short*)(dst + (size_t)px * 128 + ((oc * 2 + ((px & 7) << 4)) & 127)) = f2bf(v);
            }
    }
    // set 1 -> GAP partial sum
    {
        float bb = b2[oc];
        float s = 0.f;
#pragma unroll
        for (int mg = 0; mg < 4; ++mg)
#pragma unroll
            for (int r = 0; r < 4; ++r) s += fmaxf(acc[mg][1][r] + bb, 0.f);
        s += __shfl_xor(s, 16, 64);
        s += __shfl_xor(s, 32, 64);
        if (lane < 16) atomicAdd(&hsum[b * 64 + oc], s);
    }
}

// ---------------------------------------------------------------------------
// dw[b][n] = sum_k h[b][k]/65536 * w2[n][k] + b2[n]
__global__ void dw_gemm_kernel(const float* __restrict__ hsum, const float* __restrict__ w2,
                               const float* __restrict__ b2, float* __restrict__ dwout)
{
    __shared__ float h[64];
    int idx = blockIdx.x * 256 + threadIdx.x;
    int b = idx >> 12, n = idx & 4095;
    if (threadIdx.x < 64) h[threadIdx.x] = hsum[b * 64 + threadIdx.x] * (1.f / 65536.f);
    __syncthreads();
    float a = 0.f;
#pragma unroll
    for (int k = 0; k < 64; ++k) a = fmaf(h[k], w2[(size_t)n * 64 + k], a);
    dwout[idx] = a + b2[n];
}

// dw fp32 [b][o*64+c] -> bf16 B-fragments [b][kick(2)][owg(4)][lane][8j], k=c, n=o
__global__ void dwprep_kernel(const float* __restrict__ dwbuf, char* __restrict__ dwp)
{
    int t = blockIdx.x * 256 + threadIdx.x;   // 8192
    int jj = t & 7, lane = (t >> 3) & 63;
    int r = t >> 9;
    int owg = r & 3, kick = (r >> 2) & 1, b = r >> 3;
    int o = owg * 16 + (lane & 15);
    int c = kick * 32 + ((lane >> 4) << 3) + jj;
    *(unsigned short*)(dwp + (size_t)t * 2) = f2bf(dwbuf[b * 4096 + o * 64 + c]);
}

// ---------------------------------------------------------------------------
// FUSED conv2 + guided-filter + 1x1: per 64-px tile computes all 576 cw values
// in-register (wave w holds channels c=w*16+m16, all 9 taps via ng=j remap),
// forms y[px][c] in-register, LDS round-trip (bf16), z = y @ dw^T via MFMA.
__global__ __launch_bounds__(256, 2) void conv2yz_kernel(
    const char* __restrict__ t1, const char* __restrict__ inN,
    const char* __restrict__ Bp2, const char* __restrict__ dwp,
    const float* __restrict__ cw_b2, float* __restrict__ zout)
{
    constexpr int PPA = 66 * 128;    // 8448 plane bytes
    constexpr int BSZ = 36864;       // one B k-step (576 cols)
    __shared__ __align__(16) char pool[70400];
    char* Bs = pool;                 // [0, 36864)       K-loop
    char* As = pool + 36864;         // [36864, 62208)   K-loop
    char* Dw = pool + 62208;         // [62208, 70400)   whole kernel
    char* Pt = pool;                 // [0, 25344)       epilogue (over Bs)
    char* Ys = pool + 25344;         // [25344, 33536)   epilogue

    const int tid = threadIdx.x, lane = tid & 63, w = tid >> 6;
    const int m16 = lane & 15, q = lane >> 4;
    const int col0 = blockIdx.x * 64;
    const int row  = blockIdx.y;
    const int b    = blockIdx.z;
    const int c_lane = w * 16 + m16;

    float bias9[9];
#pragma unroll
    for (int j = 0; j < 9; ++j) bias9[j] = cw_b2[c_lane * 9 + j];

    // stage dw fragments for this batch (8 KB)
    for (int idx = tid; idx < 512; idx += 256)
        gload_lds16(dwp + (size_t)b * 8192 + idx * 16, Dw + (idx & ~63) * 16);

    // stage A (t1 rows row-1..row+1, cols col0-1..col0+64, clamped)
    const char* rowbase = t1 + ((size_t)b * 65536) * 128;
    for (int idx = tid; idx < 3 * 528; idx += 256) {
        int plane = idx / 528;
        int gr = row + plane - 1;
        if ((unsigned)gr < 256u) {
            int wb  = (idx - plane * 528) * 16;
            int pxo = wb >> 7;
            int gpx = min(max(col0 - 1 + pxo, 0), 255);
            gload_lds16(rowbase + (((size_t)gr * 256 + gpx) << 7) + (wb & 127),
                        As + (idx & ~63) * 16);
        }
    }
    __syncthreads();
    if (col0 == 0 && tid < 24)
        *(uint4*)(As + (tid / 8) * PPA + (tid & 7) * 16) = make_uint4(0, 0, 0, 0);
    if (col0 == 192 && tid < 24)
        *(uint4*)(As + (tid / 8) * PPA + 65 * 128 + (tid & 7) * 16) = make_uint4(0, 0, 0, 0);

    v4f acc[4][9];
#pragma unroll
    for (int mg = 0; mg < 4; ++mg)
#pragma unroll
        for (int ng = 0; ng < 9; ++ng) acc[mg][ng] = (v4f)(0.f);

    // ---- conv2 K-loop: cw[px][c][j] accumulates with c=w*16+m16 fixed, ng=j ----
    for (int ty = 0; ty < 3; ++ty) {
        int gr = row + ty - 1;
        if ((unsigned)gr >= 256u) continue;
        const char* plane = As + ty * PPA;
        for (int tx = 0; tx < 3; ++tx) {
            for (int ick = 0; ick < 2; ++ick) {
                __syncthreads();
                const char* bsrc = Bp2 + (size_t)((ty * 3 + tx) * 2 + ick) * BSZ;
                for (int idx = tid; idx < 2304; idx += 256)
                    gload_lds16(bsrc + idx * 16, Bs + (idx & ~63) * 16);
                __syncthreads();
                v8s af[4];
#pragma unroll
                for (int mg = 0; mg < 4; ++mg) {
                    int px  = col0 + mg * 16 + m16 + tx - 1;
                    int tpx = mg * 16 + m16 + tx;
                    int off = (ick * 64 + q * 16 + ((px & 7) << 4)) & 127;
                    af[mg] = *(const v8s*)(plane + tpx * 128 + off);
                }
#pragma unroll
                for (int ng = 0; ng < 9; ++ng) {
                    v8s bf = *(const v8s*)(Bs + (((ng << 2) + w) << 10) + (lane << 4));
#pragma unroll
                    for (int mg = 0; mg < 4; ++mg)
                        acc[mg][ng] = __builtin_amdgcn_mfma_f32_16x16x32_bf16(af[mg], bf, acc[mg][ng], 0, 0, 0);
                }
            }
        }
    }

    // ---- epilogue: stage patch (original input) over dead Bs region ----
    __syncthreads();
    const char* prow = inN + ((size_t)b * 65536) * 128;
    for (int idx = tid; idx < 3 * 528; idx += 256) {
        int plane = idx / 528;
        int gr = row + plane - 1;
        if ((unsigned)gr < 256u) {
            int wb  = (idx - plane * 528) * 16;
            int pxo = wb >> 7;
            int gpx = min(max(col0 - 1 + pxo, 0), 255);
            gload_lds16(prow + (((size_t)gr * 256 + gpx) << 7) + (wb & 127),
                        Pt + (idx & ~63) * 16);
        }
    }
    __syncthreads();
    if (col0 == 0 && tid < 24)
        *(uint4*)(Pt + (tid / 8) * PPA + (tid & 7) * 16) = make_uint4(0, 0, 0, 0);
    if (col0 == 192 && tid < 24)
        *(uint4*)(Pt + (tid / 8) * PPA + 65 * 128 + (tid & 7) * 16) = make_uint4(0, 0, 0, 0);
    __syncthreads();

    // ---- y[px][c_lane] fully in-register ----
    float yv[4][4];
#pragma unroll
    for (int mg = 0; mg < 4; ++mg)
#pragma unroll
        for (int r = 0; r < 4; ++r) yv[mg][r] = 0.f;

    for (int jy = 0; jy < 3; ++jy) {
        if ((unsigned)(row + jy - 1) >= 256u) continue;
        const char* pp = Pt + jy * PPA;
        for (int jx = 0; jx < 3; ++jx) {
            const int j = jy * 3 + jx;
            const float bj = bias9[j];
#pragma unroll
            for (int mg = 0; mg < 4; ++mg)
#pragma unroll
                for (int r = 0; r < 4; ++r) {
                    int tpx = mg * 16 + (q << 2) + r + jx;
                    unsigned short pv = *(const unsigned short*)
                        (pp + tpx * 128 + ((c_lane * 2 + (((tpx - 1) & 7) << 4)) & 127));
                    yv[mg][r] = fmaf(acc[mg][j][r] + bj, bf2f(pv), yv[mg][r]);
                }
        }
    }

    // y -> LDS (bf16, rotated) ; then z = y @ dw^T via MFMA
#pragma unroll
    for (int mg = 0; mg < 4; ++mg)
#pragma unroll
        for (int r = 0; r < 4; ++r) {
            int px_t = mg * 16 + (q << 2) + r;
            *(unsigned short*)(Ys + px_t * 128 + ((c_lane * 2 + ((px_t & 7) << 4)) & 127)) = f2bf(yv[mg][r]);
        }
    __syncthreads();

    v4f zacc[4];
#pragma unroll
    for (int mg = 0; mg < 4; ++mg) zacc[mg] = (v4f)(0.f);
#pragma unroll
    for (int kick = 0; kick < 2; ++kick) {
        v8s bf = *(const v8s*)(Dw + (((kick << 2) + w) << 10) + (lane << 4));
#pragma unroll
        for (int mg2 = 0; mg2 < 4; ++mg2) {
            int off = ((kick << 6) + (q << 4) + ((m16 & 7) << 4)) & 127;
            v8s af2 = *(const v8s*)(Ys + (mg2 * 16 + m16) * 128 + off);
            zacc[mg2] = __builtin_amdgcn_mfma_f32_16x16x32_bf16(af2, bf, zacc[mg2], 0, 0, 0);
        }
    }

    // z store: lane holds o = w*16+m16, px = mg2*16 + q*4 + r (row fixed)
    const int o = w * 16 + m16;
    float* zp = zout + (((size_t)(b * 64 + o)) << 16) + ((size_t)row << 8);
#pragma unroll
    for (int mg2 = 0; mg2 < 4; ++mg2) {
        float4 vv = make_float4(zacc[mg2][0], zacc[mg2][1], zacc[mg2][2], zacc[mg2][3]);
        *(float4*)(zp + col0 + mg2 * 16 + (q << 2)) = vv;
    }
}

// ---------------------------------------------------------------------------
// BN stats over z[b][o][hw]: grid (64 o, 8 chunks of 8192). Exact-fit indexing.
__global__ void stats_kernel(const float* __restrict__ z, float* __restrict__ s1, float* __restrict__ s2)
{
    int o = blockIdx.x, ch = blockIdx.y;
    float a1 = 0.f, a2 = 0.f;
    for (int t = threadIdx.x; t < 8192; t += 256) {
        float v0 = z[((size_t)o << 16) + (ch << 13) + t];
        float v1 = z[((size_t)(64 + o) << 16) + (ch << 13) + t];
        a1 += v0 + v1;
        a2 += v0 * v0 + v1 * v1;
    }
#pragma unroll
    for (int d = 32; d > 0; d >>= 1) { a1 += __shfl_xor(a1, d, 64); a2 += __shfl_xor(a2, d, 64); }
    __shared__ float r1[4], r2[4];
    int w = threadIdx.x >> 6;
    if ((threadIdx.x & 63) == 0) { r1[w] = a1; r2[w] = a2; }
    __syncthreads();
    if (threadIdx.x == 0) {
        atomicAdd(&s1[o], r1[0] + r1[1] + r1[2] + r1[3]);
        atomicAdd(&s2[o], r2[0] + r2[1] + r2[2] + r2[3]);
    }
}

__global__ void bn_kernel(const float* __restrict__ z, const float* __restrict__ s1,
                          const float* __restrict__ s2, const float* __restrict__ gamma,
                          const float* __restrict__ beta, float* __restrict__ outp)
{
    size_t idx = ((size_t)blockIdx.x * 256 + threadIdx.x) * 4;
    int o = (int)((idx >> 16) & 63);
    float mu  = s1[o] * (1.f / 131072.f);
    float var = s2[o] * (1.f / 131072.f) - mu * mu;
    float rs  = rsqrtf(var + 1e-5f);
    float scale = gamma[o] * rs;
    float shift = beta[o] - mu * scale;
    float4 v = *(const float4*)(z + idx);
    v.x = fmaxf(v.x * scale + shift, 0.f);
    v.y = fmaxf(v.y * scale + shift, 0.f);
    v.z = fmaxf(v.z * scale + shift, 0.f);
    v.w = fmaxf(v.w * scale + shift, 0.f);
    *(float4*)(outp + idx) = v;
}

// ---------------------------------------------------------------------------
extern "C" void kernel_launch(void* const* d_in, const int* in_sizes, int n_in,
                              void* d_out, int out_size, void* d_ws, size_t ws_size,
                              hipStream_t stream)
{
    const float* input    = (const float*)d_in[0];
    const float* guidance = (const float*)d_in[1];
    const float* cw_w1    = (const float*)d_in[2];
    const float* cw_b1    = (const float*)d_in[3];
    const float* cw_w2    = (const float*)d_in[4];
    const float* cw_b2    = (const float*)d_in[5];
    const float* dw_w1    = (const float*)d_in[6];
    const float* dw_b1    = (const float*)d_in[7];
    const float* dw_w2    = (const float*)d_in[8];
    const float* dw_b2    = (const float*)d_in[9];
    const float* gamma    = (const float*)d_in[10];
    const float* beta     = (const float*)d_in[11];

    char* ws = (char*)d_ws;
    char*  inN   = ws;                            // 16,777,216
    char*  t1    = ws + 16777216;                 // 16,777,216
    char*  Bp1   = ws + 33554432;                 // 147,456
    char*  Bpdw  = ws + 33701888;                 // 147,456
    char*  Bp2   = ws + 33849344;                 // 663,552
    float* hsum  = (float*)(ws + 34512896);       // 512
    float* s1    = (float*)(ws + 34513408);       // 256
    float* s2    = (float*)(ws + 34513664);       // 256
    float* dwbuf = (float*)(ws + 34513920);       // 32,768
    char*  dwp   = ws + 34546688;                 // 16,384

    char* X0 = (char*)d_out;   // concat bf16 lives in d_out until conv1 done

    hipMemsetAsync(hsum, 0, 1024, stream);   // hsum + s1 + s2 (contiguous)

    transpose_kernel<<<dim3(256, 2), 256, 0, stream>>>(input, guidance, X0, inN);
    prepack1_kernel<<<dim3(288, 2), 256, 0, stream>>>(cw_w1, dw_w1, Bp1, Bpdw);
    prepack2_kernel<<<1296, 256, 0, stream>>>(cw_w2, Bp2);

    conv1_mfma<<<dim3(4, 256, 2), 256, 0, stream>>>(X0, Bp1, Bpdw, cw_b1, dw_b1, t1, hsum);
    dw_gemm_kernel<<<32, 256, 0, stream>>>(hsum, dw_w2, dw_b2, dwbuf);
    dwprep_kernel<<<32, 256, 0, stream>>>(dwbuf, dwp);

    conv2yz_kernel<<<dim3(4, 256, 2), 256, 0, stream>>>(t1, inN, Bp2, dwp, cw_b2, (float*)d_out);

    stats_kernel<<<dim3(64, 8), 256, 0, stream>>>((const float*)d_out, s1, s2);
    bn_kernel<<<8192, 256, 0, stream>>>((const float*)d_out, s1, s2, gamma, beta, (float*)d_out);
}

// Round 5
// 324.295 us; speedup vs baseline: 10.4708x; 1.2207x over previous
//
#include <hip/hip_runtime.h>

typedef short v8s __attribute__((ext_vector_type(8)));
typedef float v4f __attribute__((ext_vector_type(4)));

__device__ inline unsigned short f2bf(float f) {
    unsigned u = __float_as_uint(f);
    u += 0x7fff + ((u >> 16) & 1);
    return (unsigned short)(u >> 16);
}
__device__ inline float bf2f(unsigned short h) {
    return __uint_as_float(((unsigned)h) << 16);
}

// async global->LDS, 16B per lane. LDS dest is wave-uniform base; HW adds lane*16.
__device__ inline void gload_lds16(const void* g, void* l) {
    __builtin_amdgcn_global_load_lds(
        (const __attribute__((address_space(1))) unsigned*)(unsigned long long)(uintptr_t)g,
        (__attribute__((address_space(3))) unsigned*)(unsigned)(uintptr_t)l, 16, 0, 0);
}

// ---------------------------------------------------------------------------
// transpose (LDS-staged, coalesced both ways): NCHW fp32 input+guidance ->
// X0 [b][hw][128c] rot-swizzled bf16 (256B/px) and inN [b][hw][64c] bf16 (rot&127).
// Block = 64-px tile. Phase1: coalesced reads -> LDS [px][66 words]. Phase2:
// rotation applied on LDS read, 16B/lane fully-coalesced global writes.
__global__ void transpose_kernel(const float* __restrict__ input, const float* __restrict__ guidance,
                                 char* __restrict__ X0, char* __restrict__ inN)
{
    __shared__ unsigned lds[64 * 66];
    const int tid = threadIdx.x;
    const int b = blockIdx.y;
    const size_t hw0 = (size_t)blockIdx.x * 64;

    for (int it = 0; it < 16; ++it) {
        int p  = it * 4 + (tid >> 6);     // channel-pair 0..63
        int px = tid & 63;
        size_t hw = hw0 + px;
        int c0 = 2 * p;
        float f0 = (c0 < 64) ? input[((size_t)(b * 64 + c0) << 16) + hw]
                             : guidance[((size_t)(b * 64 + c0 - 64) << 16) + hw];
        float f1 = (c0 + 1 < 64) ? input[((size_t)(b * 64 + c0 + 1) << 16) + hw]
                                 : guidance[((size_t)(b * 64 + c0 - 63) << 16) + hw];
        lds[px * 66 + p] = (unsigned)f2bf(f0) | ((unsigned)f2bf(f1) << 16);
    }
    __syncthreads();

    char* xbase = X0 + (((size_t)b * 65536 + hw0) << 8);
    for (int it = 0; it < 4; ++it) {
        int chunk = it * 256 + tid;       // 1024 chunks of 16B
        int px  = chunk >> 4;
        int ofs = (chunk & 15) << 4;
        int u   = (ofs - ((px & 7) << 4)) & 255;
        const unsigned* s = &lds[px * 66 + (u >> 2)];
        *(uint4*)(xbase + px * 256 + ofs) = make_uint4(s[0], s[1], s[2], s[3]);
    }
    char* ibase = inN + (((size_t)b * 65536 + hw0) << 7);
    for (int it = 0; it < 2; ++it) {
        int chunk = it * 256 + tid;       // 512 chunks of 16B
        int px  = chunk >> 3;
        int ofs = (chunk & 7) << 4;
        int u   = (ofs - ((px & 7) << 4)) & 127;
        const unsigned* s = &lds[px * 66 + (u >> 2)];
        *(uint4*)(ibase + px * 128 + ofs) = make_uint4(s[0], s[1], s[2], s[3]);
    }
}

// ---------------------------------------------------------------------------
// merged weight prepack.
// conv1 sets: [64][128][3][3] fp32 -> [tau][ick(4)][ng(4)][lane][8j]
// conv2:      [576][64][3][3] fp32 -> [tau][ick(2)][ng(36)][lane][8j], PERM oc=(n%64)*9+n/64
__global__ void prepack_all(const float* __restrict__ cw_w2, const float* __restrict__ cw_w1,
                            const float* __restrict__ dw_w1, char* __restrict__ Bp2,
                            char* __restrict__ Bp1, char* __restrict__ Bpdw)
{
    int bid = blockIdx.x;
    if (bid < 1296) {
        int t = bid * 256 + threadIdx.x;
        int jj = t & 7, lane = (t >> 3) & 63;
        int r2 = t >> 9;
        int ng = r2 % 36, r3 = r2 / 36;
        int ick = r3 & 1, tau = r3 >> 1;
        if (tau >= 9) return;
        int n  = ng * 16 + (lane & 15);
        int ic = ick * 32 + (lane >> 4) * 8 + jj;
        int oc = (n & 63) * 9 + (n >> 6);
        float v = cw_w2[(((size_t)oc * 64 + ic) * 3 + tau / 3) * 3 + tau % 3];
        *(unsigned short*)(Bp2 + (size_t)t * 2) = f2bf(v);
    } else {
        int s = bid - 1296;
        int set = (s >= 288);
        const float* src = set ? dw_w1 : cw_w1;
        char* dst = set ? Bpdw : Bp1;
        int t = (set ? s - 288 : s) * 256 + threadIdx.x;
        int jj = t & 7, lane = (t >> 3) & 63;
        int r2 = t >> 9;
        int ng = r2 & 3, r3 = r2 >> 2;
        int ick = r3 & 3, tau = r3 >> 2;
        if (tau >= 9) return;
        int n  = ng * 16 + (lane & 15);
        int ic = ick * 32 + (lane >> 4) * 8 + jj;
        float v = src[(((size_t)n * 128 + ic) * 3 + tau / 3) * 3 + tau % 3];
        *(unsigned short*)(dst + (size_t)t * 2) = f2bf(v);
    }
}

// ---------------------------------------------------------------------------
// conv1 fused (cw + dw paths share A): CIN=128, two 64-out B sets.
// Barrier-free K-loop: A staged once in LDS; B fragments loaded global->VGPR
// (hot in L2, every block reads the same 294 KB). LDS 50.7 KB -> 3 blocks/CU.
__global__ __launch_bounds__(256, 3) void conv1_mfma(
    const char* __restrict__ X0, const char* __restrict__ Bp1, const char* __restrict__ Bp2,
    const float* __restrict__ b1, const float* __restrict__ b2,
    char* __restrict__ t1, float* __restrict__ hsum)
{
    constexpr int PP = 66 * 256;
    __shared__ __align__(16) char As[3 * PP];      // 50688

    const int tid = threadIdx.x, lane = tid & 63, w = tid >> 6;
    const int m16 = lane & 15, q = lane >> 4;
    const int col0 = blockIdx.x * 64;
    const int row  = blockIdx.y;
    const int b    = blockIdx.z;

    const char* rowbase = X0 + ((size_t)b * 65536) * 256;
    for (int idx = tid; idx < 3 * 1056; idx += 256) {
        int plane = idx / 1056;
        int gr = row + plane - 1;
        if ((unsigned)gr < 256u) {
            int wb  = (idx - plane * 1056) * 16;
            int pxo = wb >> 8;
            int gpx = min(max(col0 - 1 + pxo, 0), 255);
            gload_lds16(rowbase + (((size_t)gr * 256 + gpx) << 8) + (wb & 255),
                        As + (idx & ~63) * 16);
        }
    }
    __syncthreads();
    if (col0 == 0 && tid < 48)
        *(uint4*)(As + (tid / 16) * PP + (tid & 15) * 16) = make_uint4(0, 0, 0, 0);
    if (col0 == 192 && tid < 48)
        *(uint4*)(As + (tid / 16) * PP + 65 * 256 + (tid & 15) * 16) = make_uint4(0, 0, 0, 0);
    __syncthreads();

    v4f acc[4][2];
#pragma unroll
    for (int mg = 0; mg < 4; ++mg) { acc[mg][0] = (v4f)(0.f); acc[mg][1] = (v4f)(0.f); }

    const int boff = (w << 10) + (lane << 4);
    for (int ty = 0; ty < 3; ++ty) {
        int gr = row + ty - 1;
        if ((unsigned)gr >= 256u) continue;
        const char* plane = As + ty * PP;
        for (int tx = 0; tx < 3; ++tx) {
#pragma unroll
            for (int ick = 0; ick < 4; ++ick) {
                const int kstep = (ty * 3 + tx) * 4 + ick;
                v8s af[4];
#pragma unroll
                for (int mg = 0; mg < 4; ++mg) {
                    int px  = col0 + mg * 16 + m16 + tx - 1;
                    int tpx = mg * 16 + m16 + tx;
                    int off = (ick * 64 + q * 16 + ((px & 7) << 4)) & 255;
                    af[mg] = *(const v8s*)(plane + tpx * 256 + off);
                }
                v8s bf0 = *(const v8s*)(Bp1 + (size_t)kstep * 4096 + boff);
                v8s bf1 = *(const v8s*)(Bp2 + (size_t)kstep * 4096 + boff);
#pragma unroll
                for (int mg = 0; mg < 4; ++mg)
                    acc[mg][0] = __builtin_amdgcn_mfma_f32_16x16x32_bf16(af[mg], bf0, acc[mg][0], 0, 0, 0);
#pragma unroll
                for (int mg = 0; mg < 4; ++mg)
                    acc[mg][1] = __builtin_amdgcn_mfma_f32_16x16x32_bf16(af[mg], bf1, acc[mg][1], 0, 0, 0);
            }
        }
    }

    const int oc = w * 16 + m16;
    {
        float bb = b1[oc];
        char* dst = t1 + (((size_t)(b * 256 + row)) << 8) * 128;
#pragma unroll
        for (int mg = 0; mg < 4; ++mg)
#pragma unroll
            for (int r = 0; r < 4; ++r) {
                int px = col0 + mg * 16 + (q << 2) + r;
                float v = fmaxf(acc[mg][0][r] + bb, 0.f);
                *(unsigned short*)(dst + (size_t)px * 128 + ((oc * 2 + ((px & 7) << 4)) & 127)) = f2bf(v);
            }
    }
    {
        float bb = b2[oc];
        float s = 0.f;
#pragma unroll
        for (int mg = 0; mg < 4; ++mg)
#pragma unroll
            for (int r = 0; r < 4; ++r) s += fmaxf(acc[mg][1][r] + bb, 0.f);
        s += __shfl_xor(s, 16, 64);
        s += __shfl_xor(s, 32, 64);
        if (lane < 16) atomicAdd(&hsum[b * 64 + oc], s);
    }
}

// ---------------------------------------------------------------------------
// fused GAP 1x1 conv + fragment prepack:
// dwp[b][kick(2)][owg(4)][lane][8j] = bf16( sum_k h[b][k]/65536 * w2[o*64+c][k] + b2[o*64+c] )
__global__ void dwfused_kernel(const float* __restrict__ hsum, const float* __restrict__ w2,
                               const float* __restrict__ b2, char* __restrict__ dwp)
{
    __shared__ float h[64];
    int t = blockIdx.x * 256 + threadIdx.x;   // 8192 total
    int b = t >> 12;
    if (threadIdx.x < 64) h[threadIdx.x] = hsum[b * 64 + threadIdx.x] * (1.f / 65536.f);
    __syncthreads();
    int jj = t & 7, lane = (t >> 3) & 63;
    int r = t >> 9;
    int owg = r & 3, kick = (r >> 2) & 1;
    int o = owg * 16 + (lane & 15);
    int c = kick * 32 + ((lane >> 4) << 3) + jj;
    int n = o * 64 + c;
    float a = 0.f;
#pragma unroll
    for (int k = 0; k < 64; ++k) a = fmaf(h[k], w2[(size_t)n * 64 + k], a);
    *(unsigned short*)(dwp + (size_t)t * 2) = f2bf(a + b2[n]);
}

// ---------------------------------------------------------------------------
// FUSED conv2 + guided-filter + 1x1. Barrier-free K-loop: A (t1) + patch (inN)
// + dw fragments staged once; B fragments direct global->VGPR from L2-hot Bp2.
__global__ __launch_bounds__(256, 2) void conv2yz_kernel(
    const char* __restrict__ t1, const char* __restrict__ inN,
    const char* __restrict__ Bp2, const char* __restrict__ dwp,
    const float* __restrict__ cw_b2, float* __restrict__ zout)
{
    constexpr int PPA = 66 * 128;    // 8448 plane bytes
    __shared__ __align__(16) char As[3 * PPA];   // 25344
    __shared__ __align__(16) char Pt[3 * PPA];   // 25344
    __shared__ __align__(16) char Ys[8192];
    __shared__ __align__(16) char Dw[8192];

    const int tid = threadIdx.x, lane = tid & 63, w = tid >> 6;
    const int m16 = lane & 15, q = lane >> 4;
    const int col0 = blockIdx.x * 64;
    const int row  = blockIdx.y;
    const int b    = blockIdx.z;
    const int c_lane = w * 16 + m16;

    // stage dw fragments (8 KB), A (t1) and patch (inN) halo tiles
    for (int idx = tid; idx < 512; idx += 256)
        gload_lds16(dwp + (size_t)b * 8192 + idx * 16, Dw + (idx & ~63) * 16);
    const char* arow = t1  + ((size_t)b * 65536) * 128;
    const char* prow = inN + ((size_t)b * 65536) * 128;
    for (int idx = tid; idx < 3 * 528; idx += 256) {
        int plane = idx / 528;
        int gr = row + plane - 1;
        if ((unsigned)gr < 256u) {
            int wb  = (idx - plane * 528) * 16;
            int pxo = wb >> 7;
            int gpx = min(max(col0 - 1 + pxo, 0), 255);
            size_t goff = (((size_t)gr * 256 + gpx) << 7) + (wb & 127);
            gload_lds16(arow + goff, As + (idx & ~63) * 16);
            gload_lds16(prow + goff, Pt + (idx & ~63) * 16);
        }
    }
    __syncthreads();
    if (col0 == 0 && tid < 24) {
        *(uint4*)(As + (tid / 8) * PPA + (tid & 7) * 16) = make_uint4(0, 0, 0, 0);
        *(uint4*)(Pt + (tid / 8) * PPA + (tid & 7) * 16) = make_uint4(0, 0, 0, 0);
    }
    if (col0 == 192 && tid < 24) {
        *(uint4*)(As + (tid / 8) * PPA + 65 * 128 + (tid & 7) * 16) = make_uint4(0, 0, 0, 0);
        *(uint4*)(Pt + (tid / 8) * PPA + 65 * 128 + (tid & 7) * 16) = make_uint4(0, 0, 0, 0);
    }
    __syncthreads();

    float bias9[9];
#pragma unroll
    for (int j = 0; j < 9; ++j) bias9[j] = cw_b2[c_lane * 9 + j];

    v4f acc[4][9];
#pragma unroll
    for (int mg = 0; mg < 4; ++mg)
#pragma unroll
        for (int ng = 0; ng < 9; ++ng) acc[mg][ng] = (v4f)(0.f);

    // ---- barrier-free conv2 K-loop ----
    const int boff = (w << 10) + (lane << 4);
    for (int ty = 0; ty < 3; ++ty) {
        int gr = row + ty - 1;
        if ((unsigned)gr >= 256u) continue;
        const char* plane = As + ty * PPA;
#pragma unroll 1
        for (int tx = 0; tx < 3; ++tx) {
#pragma unroll
            for (int ick = 0; ick < 2; ++ick) {
                const int kstep = (ty * 3 + tx) * 2 + ick;
                v8s af[4];
#pragma unroll
                for (int mg = 0; mg < 4; ++mg) {
                    int px  = col0 + mg * 16 + m16 + tx - 1;
                    int tpx = mg * 16 + m16 + tx;
                    int off = (ick * 64 + q * 16 + ((px & 7) << 4)) & 127;
                    af[mg] = *(const v8s*)(plane + tpx * 128 + off);
                }
                const char* bbase = Bp2 + (size_t)kstep * 36864 + boff;
#pragma unroll
                for (int ng = 0; ng < 9; ++ng) {
                    v8s bf = *(const v8s*)(bbase + (ng << 12));
#pragma unroll
                    for (int mg = 0; mg < 4; ++mg)
                        acc[mg][ng] = __builtin_amdgcn_mfma_f32_16x16x32_bf16(af[mg], bf, acc[mg][ng], 0, 0, 0);
                }
            }
        }
    }

    // ---- y[px][c_lane] in-register from patch ----
    float yv[4][4];
#pragma unroll
    for (int mg = 0; mg < 4; ++mg)
#pragma unroll
        for (int r = 0; r < 4; ++r) yv[mg][r] = 0.f;

    for (int jy = 0; jy < 3; ++jy) {
        if ((unsigned)(row + jy - 1) >= 256u) continue;
        const char* pp = Pt + jy * PPA;
        for (int jx = 0; jx < 3; ++jx) {
            const int j = jy * 3 + jx;
            const float bj = bias9[j];
#pragma unroll
            for (int mg = 0; mg < 4; ++mg)
#pragma unroll
                for (int r = 0; r < 4; ++r) {
                    int tpx = mg * 16 + (q << 2) + r + jx;
                    unsigned short pv = *(const unsigned short*)
                        (pp + tpx * 128 + ((c_lane * 2 + (((tpx - 1) & 7) << 4)) & 127));
                    yv[mg][r] = fmaf(acc[mg][j][r] + bj, bf2f(pv), yv[mg][r]);
                }
        }
    }

    // y -> LDS (bf16, rotated) ; z = y @ dw^T via MFMA
#pragma unroll
    for (int mg = 0; mg < 4; ++mg)
#pragma unroll
        for (int r = 0; r < 4; ++r) {
            int px_t = mg * 16 + (q << 2) + r;
            *(unsigned short*)(Ys + px_t * 128 + ((c_lane * 2 + ((px_t & 7) << 4)) & 127)) = f2bf(yv[mg][r]);
        }
    __syncthreads();

    v4f zacc[4];
#pragma unroll
    for (int mg = 0; mg < 4; ++mg) zacc[mg] = (v4f)(0.f);
#pragma unroll
    for (int kick = 0; kick < 2; ++kick) {
        v8s bf = *(const v8s*)(Dw + (((kick << 2) + w) << 10) + (lane << 4));
#pragma unroll
        for (int mg2 = 0; mg2 < 4; ++mg2) {
            int off = ((kick << 6) + (q << 4) + ((m16 & 7) << 4)) & 127;
            v8s af2 = *(const v8s*)(Ys + (mg2 * 16 + m16) * 128 + off);
            zacc[mg2] = __builtin_amdgcn_mfma_f32_16x16x32_bf16(af2, bf, zacc[mg2], 0, 0, 0);
        }
    }

    const int o = w * 16 + m16;
    float* zp = zout + (((size_t)(b * 64 + o)) << 16) + ((size_t)row << 8);
#pragma unroll
    for (int mg2 = 0; mg2 < 4; ++mg2) {
        float4 vv = make_float4(zacc[mg2][0], zacc[mg2][1], zacc[mg2][2], zacc[mg2][3]);
        *(float4*)(zp + col0 + mg2 * 16 + (q << 2)) = vv;
    }
}

// ---------------------------------------------------------------------------
__global__ void stats_kernel(const float* __restrict__ z, float* __restrict__ s1, float* __restrict__ s2)
{
    int o = blockIdx.x, ch = blockIdx.y;
    float a1 = 0.f, a2 = 0.f;
    for (int t = threadIdx.x; t < 8192; t += 256) {
        float v0 = z[((size_t)o << 16) + (ch << 13) + t];
        float v1 = z[((size_t)(64 + o) << 16) + (ch << 13) + t];
        a1 += v0 + v1;
        a2 += v0 * v0 + v1 * v1;
    }
#pragma unroll
    for (int d = 32; d > 0; d >>= 1) { a1 += __shfl_xor(a1, d, 64); a2 += __shfl_xor(a2, d, 64); }
    __shared__ float r1[4], r2[4];
    int w = threadIdx.x >> 6;
    if ((threadIdx.x & 63) == 0) { r1[w] = a1; r2[w] = a2; }
    __syncthreads();
    if (threadIdx.x == 0) {
        atomicAdd(&s1[o], r1[0] + r1[1] + r1[2] + r1[3]);
        atomicAdd(&s2[o], r2[0] + r2[1] + r2[2] + r2[3]);
    }
}

__global__ void bn_kernel(const float* __restrict__ z, const float* __restrict__ s1,
                          const float* __restrict__ s2, const float* __restrict__ gamma,
                          const float* __restrict__ beta, float* __restrict__ outp)
{
    size_t idx = ((size_t)blockIdx.x * 256 + threadIdx.x) * 4;
    int o = (int)((idx >> 16) & 63);
    float mu  = s1[o] * (1.f / 131072.f);
    float var = s2[o] * (1.f / 131072.f) - mu * mu;
    float rs  = rsqrtf(var + 1e-5f);
    float scale = gamma[o] * rs;
    float shift = beta[o] - mu * scale;
    float4 v = *(const float4*)(z + idx);
    v.x = fmaxf(v.x * scale + shift, 0.f);
    v.y = fmaxf(v.y * scale + shift, 0.f);
    v.z = fmaxf(v.z * scale + shift, 0.f);
    v.w = fmaxf(v.w * scale + shift, 0.f);
    *(float4*)(outp + idx) = v;
}

// ---------------------------------------------------------------------------
extern "C" void kernel_launch(void* const* d_in, const int* in_sizes, int n_in,
                              void* d_out, int out_size, void* d_ws, size_t ws_size,
                              hipStream_t stream)
{
    const float* input    = (const float*)d_in[0];
    const float* guidance = (const float*)d_in[1];
    const float* cw_w1    = (const float*)d_in[2];
    const float* cw_b1    = (const float*)d_in[3];
    const float* cw_w2    = (const float*)d_in[4];
    const float* cw_b2    = (const float*)d_in[5];
    const float* dw_w1    = (const float*)d_in[6];
    const float* dw_b1    = (const float*)d_in[7];
    const float* dw_w2    = (const float*)d_in[8];
    const float* dw_b2    = (const float*)d_in[9];
    const float* gamma    = (const float*)d_in[10];
    const float* beta     = (const float*)d_in[11];

    char* ws = (char*)d_ws;
    char*  inN   = ws;                            // 16,777,216
    char*  t1    = ws + 16777216;                 // 16,777,216
    char*  Bp1   = ws + 33554432;                 // 147,456
    char*  Bpdw  = ws + 33701888;                 // 147,456
    char*  Bp2   = ws + 33849344;                 // 663,552
    float* hsum  = (float*)(ws + 34512896);       // 512
    float* s1    = (float*)(ws + 34513408);       // 256
    float* s2    = (float*)(ws + 34513664);       // 256
    char*  dwp   = ws + 34513920;                 // 16,384

    char* X0 = (char*)d_out;   // concat bf16 lives in d_out until conv1 done

    hipMemsetAsync(hsum, 0, 1024, stream);   // hsum + s1 + s2 (contiguous)

    transpose_kernel<<<dim3(1024, 2), 256, 0, stream>>>(input, guidance, X0, inN);
    prepack_all<<<1872, 256, 0, stream>>>(cw_w2, cw_w1, dw_w1, Bp2, Bp1, Bpdw);

    conv1_mfma<<<dim3(4, 256, 2), 256, 0, stream>>>(X0, Bp1, Bpdw, cw_b1, dw_b1, t1, hsum);
    dwfused_kernel<<<32, 256, 0, stream>>>(hsum, dw_w2, dw_b2, dwp);

    conv2yz_kernel<<<dim3(4, 256, 2), 256, 0, stream>>>(t1, inN, Bp2, dwp, cw_b2, (float*)d_out);

    stats_kernel<<<dim3(64, 8), 256, 0, stream>>>((const float*)d_out, s1, s2);
    bn_kernel<<<8192, 256, 0, stream>>>((const float*)d_out, s1, s2, gamma, beta, (float*)d_out);
}